// Round 8
// baseline (3825.389 us; speedup 1.0000x reference)
//
#include <hip/hip_runtime.h>

// RNN scan: h <- tanh(x_t @ W_ih^T + h @ W_hh^T + b), 2048 steps.
// v8: MFMA recurrence, 16 batches/block (16 blocks x 512 thr, 8 waves).
// v4/v5/v7 pinned: interval = per-SIMD VALU issue + ~570cy fixed floor, no
// overlap. Only MFMA moves per-batch work off the VALU stream. Per step:
// H_new[16x128] = tanh(H @ Whh^T + XW) via 12 mfma_16x16x32_bf16 (hi/lo
// 3-pass) + 12 more for next-chunk xw. H lives in LDS as bf16 hi/lo planes;
// xw chunk lives in C-layout registers (bias folded). Layout composition:
// A-frag = [batch][k] rows (proven compute_xw pattern), B-frag = W rows
// (proven), C rows = batch = next A rows, xw C-frag = recurrence C-init.
// x staged per 8-step chunk (128KB dbuf), 2-step-lagged global->LDS pipeline.

#define BATCH 256
#define SEQ   2048
#define HID   128
#define CH    8
#define NCHUNK (SEQ / CH)
#define BPB   16

typedef __attribute__((ext_vector_type(8))) short bf16x8;
typedef __attribute__((ext_vector_type(4))) float f32x4;

__device__ __forceinline__ float tanh_fast(float x) {
    x = fminf(fmaxf(x, -12.0f), 12.0f);
    float e = __expf(2.0f * x);
    return 1.0f - __fdividef(2.0f, e + 1.0f);
}

// split float -> (hi, lo) bf16 pair (~16 mantissa bits), rounded hi
__device__ __forceinline__ void bf16_split(float v, short& hi, short& lo) {
    unsigned u = __float_as_uint(v);
    unsigned hb = (u + 0x8000u) & 0xFFFF0000u;
    float hf = __uint_as_float(hb);
    float r = v - hf;
    hi = (short)(hb >> 16);
    lo = (short)((__float_as_uint(r) + 0x8000u) >> 16);
}

__global__ __launch_bounds__(512, 2) void rnn_scan_kernel(
    const float* __restrict__ x,    // [B, S, 128]
    const float* __restrict__ Wih,  // [128, 128]
    const float* __restrict__ bih,  // [128]
    const float* __restrict__ Whh,  // [128, 128]
    const float* __restrict__ bhh,  // [128]
    float* __restrict__ out)        // [B, 128]
{
    const int b0 = blockIdx.x * BPB;
    const int t = threadIdx.x;
    const int lane = t & 63;
    const int w = t >> 6;          // wave 0..7: owns h-cols 16w..16w+15
    const int l15 = lane & 15;
    const int l16 = lane >> 4;

    // [buf][plane hi/lo][step][batch][k]  (128 KB)
    __shared__ __align__(16) ushort xlds[2][2][CH][BPB][HID];
    // [buf][plane hi/lo][batch][k]        (16 KB)
    __shared__ __align__(16) ushort hlds[2][2][BPB][HID];
    char* const xbase = (char*)&xlds[0][0][0][0][0];
    char* const hbase = (char*)&hlds[0][0][0][0];

    // ---- B fragments (16x16x32): lane holds B[k=l16*8+j][col=l15+16w] =
    // W[16w+l15][kk*32+l16*8+j] -> 8 consecutive floats of a W row ----
    const int nc = (w << 4) + l15;              // output h-col of this lane
    const float biasv = bih[nc] + bhh[nc];
    const f32x4 bias4 = {biasv, biasv, biasv, biasv};
    bf16x8 wih_h[4], wih_l[4], whh_h[4], whh_l[4];
    auto build_frag = [&](const float* src, bf16x8& fh, bf16x8& fl) {
        float4 u0 = *(const float4*)(src);
        float4 u1 = *(const float4*)(src + 4);
        short hh, ll;
        bf16_split(u0.x, hh, ll); fh[0] = hh; fl[0] = ll;
        bf16_split(u0.y, hh, ll); fh[1] = hh; fl[1] = ll;
        bf16_split(u0.z, hh, ll); fh[2] = hh; fl[2] = ll;
        bf16_split(u0.w, hh, ll); fh[3] = hh; fl[3] = ll;
        bf16_split(u1.x, hh, ll); fh[4] = hh; fl[4] = ll;
        bf16_split(u1.y, hh, ll); fh[5] = hh; fl[5] = ll;
        bf16_split(u1.z, hh, ll); fh[6] = hh; fl[6] = ll;
        bf16_split(u1.w, hh, ll); fh[7] = hh; fl[7] = ll;
    };
#pragma unroll
    for (int kk = 0; kk < 4; ++kk) {
        build_frag(Wih + nc * HID + kk * 32 + (l16 << 3), wih_h[kk], wih_l[kk]);
        build_frag(Whh + nc * HID + kk * 32 + (l16 << 3), whh_h[kk], whh_l[kk]);
    }

    // ---- address registers (XOR swizzle applied AFTER full low-bit sum) ----
    const int swzA = (l15 & 7) << 4;
    char* px[2][4];   // x A-frag read, per buf
    char* ph[4];      // H A-frag read (buf/plane via immediate)
#pragma unroll
    for (int kk = 0; kk < 4; ++kk) {
        const int av = l15 * 256 + (((kk * 64) + (l16 * 16)) ^ swzA);
        px[0][kk] = xbase + av;
        px[1][kk] = xbase + 65536 + av;
        ph[kk]    = hbase + av;
    }
    // H write: C-layout -> lane writes rows m=l16*4+r, col nc
    char* whp[4];
#pragma unroll
    for (int r = 0; r < 4; ++r) {
        const int mr = (l16 << 2) + r;
        whp[r] = hbase + ((mr * 256 + nc * 2) ^ ((mr & 7) << 4));
    }
    // staging write: thread t -> batch bt=t>>5, k0=(t&31)*4 (8B, swizzled)
    const int bt = t >> 5;
    const int wsoff = bt * 256 + ((((t & 31) << 3)) ^ ((bt & 7) << 4));
    char* ws[2] = { xbase + wsoff, xbase + 65536 + wsoff };

    // staging global source: x[(b0+bt)][gs][k0..k0+3]
    const float* xg = x + (size_t)(b0 + bt) * (SEQ * HID) + ((t & 31) << 2);

    // split a float4 into hi/lo bf16 pairs and store 8B to tile slot
    auto write_tile = [&](char* wp, int tile, float4 v) {
        unsigned u0 = __float_as_uint(v.x), u1 = __float_as_uint(v.y);
        unsigned u2 = __float_as_uint(v.z), u3 = __float_as_uint(v.w);
        unsigned h0 = u0 & 0xFFFF0000u, h1 = u1 & 0xFFFF0000u;
        unsigned h2 = u2 & 0xFFFF0000u, h3 = u3 & 0xFFFF0000u;
        uint2 hp, lp;
        hp.x = (u0 >> 16) | h1;
        hp.y = (u2 >> 16) | h3;
        float l0f = v.x - __uint_as_float(h0), l1f = v.y - __uint_as_float(h1);
        float l2f = v.z - __uint_as_float(h2), l3f = v.w - __uint_as_float(h3);
        lp.x = (__float_as_uint(l0f) >> 16) | (__float_as_uint(l1f) & 0xFFFF0000u);
        lp.y = (__float_as_uint(l2f) >> 16) | (__float_as_uint(l3f) & 0xFFFF0000u);
        *(uint2*)(wp + tile * 4096)         = hp;   // hi plane
        *(uint2*)(wp + 32768 + tile * 4096) = lp;   // lo plane
    };

    // ---- prologue: stage chunks 0 -> buf0, 1 -> buf1; zero H buf0 ----
    float4 qc0, qc1;
#pragma unroll
    for (int cc = 0; cc < 2; ++cc) {
        const float* pgc = xg + cc * (CH * HID);
#pragma unroll
        for (int s = 0; s < CH; ++s) {
            float4 q = *(const float4*)(pgc + s * HID);
            write_tile(ws[cc], s, q);
            if (cc == 1 && s == 6) qc0 = q;   // carried lag registers
            if (cc == 1 && s == 7) qc1 = q;
        }
    }
    ((float4*)hbase)[t] = make_float4(0.f, 0.f, 0.f, 0.f);  // 512*16B = hlds[0]
    __syncthreads();

    // ---- prologue xw(chunk 0) -> xwA regs (reads buf0) ----
    f32x4 xwA[CH], xwB[CH];
#pragma unroll
    for (int s = 0; s < CH; ++s) {
        f32x4 c0 = bias4, c1 = {0,0,0,0}, c2 = {0,0,0,0};
#pragma unroll
        for (int kk = 0; kk < 4; ++kk) {
            bf16x8 xh = *(const bf16x8*)(px[0][kk] + s * 4096);
            bf16x8 xl = *(const bf16x8*)(px[0][kk] + 32768 + s * 4096);
            c0 = __builtin_amdgcn_mfma_f32_16x16x32_bf16(xh, wih_h[kk], c0, 0, 0, 0);
            c1 = __builtin_amdgcn_mfma_f32_16x16x32_bf16(xh, wih_l[kk], c1, 0, 0, 0);
            c2 = __builtin_amdgcn_mfma_f32_16x16x32_bf16(xl, wih_h[kk], c2, 0, 0, 0);
        }
        xwA[s] = c0 + c1 + c2;
    }
    const float* pgm = xg + 2 * (CH * HID);   // global base of chunk 2

// One 8-step chunk. PAR = nn&1 (literal). xwc = this chunk's xw regs,
// xwn = next chunk's (computed here). Staging: loads chunk nn+2 tile s at
// step s, writes lag 2 steps (tiles 6,7 of chunk nn+1 land at steps 0,1).
#define CHUNK_BODY(nn, PAR, xwc, xwn)                                          \
    {                                                                          \
        const bool gx = (nn) + 1 < NCHUNK;                                     \
        const bool gs = (nn) + 2 < NCHUNK;                                     \
        float4 q[CH];                                                          \
        _Pragma("unroll")                                                      \
        for (int s = 0; s < CH; ++s) {                                         \
            if (gs) q[s] = *(const float4*)(pgm + s * HID);                    \
            if (s == 0) { if (gx) write_tile(ws[(PAR) ^ 1], 6, qc0); }         \
            if (s == 1) { if (gx) write_tile(ws[(PAR) ^ 1], 7, qc1); }         \
            if (s >= 2) { if (gs) write_tile(ws[PAR], s - 2, q[s - 2]); }      \
            { /* recurrence: u = H(buf s&1) @ Whh^T + xwc[s] */                \
                const int p = s & 1;                                           \
                f32x4 a0 = xwc[s], a1 = {0,0,0,0}, a2 = {0,0,0,0};             \
                _Pragma("unroll")                                              \
                for (int kk = 0; kk < 4; ++kk) {                               \
                    bf16x8 hh = *(const bf16x8*)(ph[kk] + p * 8192);           \
                    bf16x8 hl = *(const bf16x8*)(ph[kk] + p * 8192 + 4096);    \
                    a0 = __builtin_amdgcn_mfma_f32_16x16x32_bf16(hh, whh_h[kk], a0, 0, 0, 0); \
                    a1 = __builtin_amdgcn_mfma_f32_16x16x32_bf16(hh, whh_l[kk], a1, 0, 0, 0); \
                    a2 = __builtin_amdgcn_mfma_f32_16x16x32_bf16(hl, whh_h[kk], a2, 0, 0, 0); \
                }                                                              \
                f32x4 u4 = a0 + a1 + a2;                                       \
                _Pragma("unroll")                                              \
                for (int r = 0; r < 4; ++r) {                                  \
                    float hv = tanh_fast(u4[r]);                               \
                    unsigned ub = __float_as_uint(hv);                         \
                    unsigned hb = ub & 0xFFFF0000u;                            \
                    float lf = hv - __uint_as_float(hb);                       \
                    *(ushort*)(whp[r] + ((p ^ 1) * 8192)) = (ushort)(ub >> 16); \
                    *(ushort*)(whp[r] + ((p ^ 1) * 8192 + 4096)) =             \
                        (ushort)(__float_as_uint(lf) >> 16);                   \
                }                                                              \
            }                                                                  \
            if (gx) { /* xw for chunk nn+1, tile s (reads buf PAR^1) */        \
                f32x4 c0 = bias4, c1 = {0,0,0,0}, c2 = {0,0,0,0};              \
                _Pragma("unroll")                                              \
                for (int kk = 0; kk < 4; ++kk) {                               \
                    bf16x8 xh = *(const bf16x8*)(px[(PAR) ^ 1][kk] + s * 4096); \
                    bf16x8 xl = *(const bf16x8*)(px[(PAR) ^ 1][kk] + 32768 + s * 4096); \
                    c0 = __builtin_amdgcn_mfma_f32_16x16x32_bf16(xh, wih_h[kk], c0, 0, 0, 0); \
                    c1 = __builtin_amdgcn_mfma_f32_16x16x32_bf16(xh, wih_l[kk], c1, 0, 0, 0); \
                    c2 = __builtin_amdgcn_mfma_f32_16x16x32_bf16(xl, wih_h[kk], c2, 0, 0, 0); \
                }                                                              \
                xwn[s] = c0 + c1 + c2;                                         \
            }                                                                  \
            __syncthreads();                                                   \
        }                                                                      \
        if (gs) { qc0 = q[6]; qc1 = q[7]; }                                    \
        pgm += CH * HID;                                                       \
    }

#pragma unroll 1
    for (int nn = 0; nn < NCHUNK; nn += 2) {
        CHUNK_BODY(nn,     0, xwA, xwB);
        CHUNK_BODY(nn + 1, 1, xwB, xwA);
    }
#undef CHUNK_BODY

    // ---- epilogue: H final in buf 0 (2048 = even steps). 4 cols/thread ----
    {
        const int c4 = (t & 31) << 2;
        const int rd = bt * 256 + ((((t & 31) << 3)) ^ ((bt & 7) << 4));
        uint2 hp = *(const uint2*)(hbase + rd);
        uint2 lp = *(const uint2*)(hbase + rd + 4096);
        float4 o;
        o.x = __uint_as_float(hp.x << 16) + __uint_as_float(lp.x << 16);
        o.y = __uint_as_float(hp.x & 0xFFFF0000u) + __uint_as_float(lp.x & 0xFFFF0000u);
        o.z = __uint_as_float(hp.y << 16) + __uint_as_float(lp.y << 16);
        o.w = __uint_as_float(hp.y & 0xFFFF0000u) + __uint_as_float(lp.y & 0xFFFF0000u);
        *(float4*)(out + (size_t)(b0 + bt) * HID + c4) = o;
    }
}

extern "C" void kernel_launch(void* const* d_in, const int* in_sizes, int n_in,
                              void* d_out, int out_size, void* d_ws, size_t ws_size,
                              hipStream_t stream) {
    const float* x   = (const float*)d_in[0];
    const float* Wih = (const float*)d_in[1];
    const float* bih = (const float*)d_in[2];
    const float* Whh = (const float*)d_in[3];
    const float* bhh = (const float*)d_in[4];
    float* out = (float*)d_out;

    rnn_scan_kernel<<<BATCH / BPB, 512, 0, stream>>>(x, Wih, bih, Whh, bhh, out);
}